// Round 12
// baseline (236.658 us; speedup 1.0000x reference)
//
#include <hip/hip_runtime.h>

#define DMODEL 1024
#define NHEADS 16
#define HDIM   64
#define BATCH  2
#define SEQ    2048
#define MROWS  (BATCH*SEQ)

typedef __bf16 bf16x8 __attribute__((ext_vector_type(8)));
typedef __bf16 bf16x4 __attribute__((ext_vector_type(4)));
typedef float floatx4 __attribute__((ext_vector_type(4)));

typedef const __attribute__((address_space(1))) void gvoid;
typedef __attribute__((address_space(3))) void lvoid;

// Q pre-scale: 1/sqrt(64) * log2(e), folded into the QKV GEMM epilogue.
#define QSCALE 0.18033688011112042f

// Single cast kernel: x (1048576 float4) then Wq/Wk/Wv/Wo (262144 float4 each).
__global__ void cast_all(const float* __restrict__ x,
                         const float* __restrict__ wq, const float* __restrict__ wk,
                         const float* __restrict__ wv, const float* __restrict__ wo,
                         __bf16* __restrict__ xb, __bf16* __restrict__ wqb,
                         __bf16* __restrict__ wkb, __bf16* __restrict__ wvb,
                         __bf16* __restrict__ wob)
{
  const int i = blockIdx.x * 256 + threadIdx.x;
  const float* s; __bf16* o; int off;
  if (i < MROWS*DMODEL/4) { s = x; o = xb; off = i; }
  else {
    const int r = i - MROWS*DMODEL/4;
    const int w = r >> 18;
    off = r & 262143;
    s = (w == 0) ? wq : (w == 1) ? wk : (w == 2) ? wv : wo;
    o = (w == 0) ? wqb : (w == 1) ? wkb : (w == 2) ? wvb : wob;
  }
  const float4 f = ((const float4*)s)[off];
  bf16x4 v = {(__bf16)f.x, (__bf16)f.y, (__bf16)f.z, (__bf16)f.w};
  *(bf16x4*)(o + off*4) = v;
}

// NT GEMM (unchanged): double-buffered gload_lds + vmcnt(4).
template<int MODE>
__global__ __launch_bounds__(256, 3)
void gemm_nt(const unsigned short* __restrict__ A,
             const unsigned short* __restrict__ W0,
             const unsigned short* __restrict__ W1,
             const unsigned short* __restrict__ W2,
             const float* __restrict__ b0,
             const float* __restrict__ b1,
             const float* __restrict__ b2,
             unsigned short* __restrict__ qout,
             unsigned short* __restrict__ kout,
             unsigned short* __restrict__ vout,
             float* __restrict__ outf)
{
  const int K = DMODEL;
  __shared__ unsigned short As[2][128*32];
  __shared__ unsigned short Bs[2][128*32];
  const int tid  = threadIdx.x;
  const int wid  = tid >> 6;
  const int lane = tid & 63;

  const int lin = blockIdx.x;
  const int wg  = (MODE == 0) ? ((lin & 7)*96 + (lin >> 3))
                              : ((lin & 7)*32 + (lin >> 3));
  const int bx  = (MODE == 0) ? (wg % 24) : (wg & 7);
  const int by  = (MODE == 0) ? (wg / 24) : (wg >> 3);
  const int brow = by * 128;
  const int bcol = bx * 128;
  const int wr = (wid >> 1) * 64;
  const int wc = (wid & 1) * 64;

  int which = 0;
  const unsigned short* Bw = W0;
  const float* bias = b0;
  int bcolL = bcol;
  if (MODE == 0) {
    which = bcol >> 10;
    Bw   = which == 0 ? W0 : which == 1 ? W1 : W2;
    bias = which == 0 ? b0 : which == 1 ? b1 : b2;
    bcolL = bcol & 1023;
  }

  floatx4 acc[4][4] = {};

  const int sr = wid*16 + (lane >> 2);
  const int sc = (lane & 3) * 8;
  const int fr = lane & 15;
  const int fk = (lane >> 4) * 8;

#define GSTAGE(KT, B) do {                                                     \
    _Pragma("unroll")                                                          \
    for (int i_ = 0; i_ < 2; ++i_) {                                           \
      __builtin_amdgcn_global_load_lds(                                        \
          (gvoid*)(A + (size_t)(brow + i_*64 + sr)*K + (KT) + sc),             \
          (lvoid*)(As[B] + i_*2048 + wid*512), 16, 0, 0);                      \
      __builtin_amdgcn_global_load_lds(                                        \
          (gvoid*)(Bw + (size_t)(bcolL + i_*64 + sr)*K + (KT) + sc),           \
          (lvoid*)(Bs[B] + i_*2048 + wid*512), 16, 0, 0);                      \
    }                                                                          \
  } while (0)

  GSTAGE(0, 0);

  for (int kt = 0; kt < K; kt += 32) {
    const int cur = (kt >> 5) & 1;
    if (kt + 32 < K) {
      GSTAGE(kt + 32, cur ^ 1);
      asm volatile("s_waitcnt vmcnt(4)" ::: "memory");
    } else {
      asm volatile("s_waitcnt vmcnt(0)" ::: "memory");
    }
    __builtin_amdgcn_s_barrier();
    __builtin_amdgcn_sched_barrier(0);

    bf16x8 af[4], bfv[4];
#pragma unroll
    for (int m = 0; m < 4; ++m)
      af[m] = *(const bf16x8*)(As[cur] + (wr + m*16 + fr)*32 + fk);
#pragma unroll
    for (int n = 0; n < 4; ++n)
      bfv[n] = *(const bf16x8*)(Bs[cur] + (wc + n*16 + fr)*32 + fk);
    __builtin_amdgcn_s_setprio(1);
#pragma unroll
    for (int m = 0; m < 4; ++m)
#pragma unroll
      for (int n = 0; n < 4; ++n)
        acc[m][n] = __builtin_amdgcn_mfma_f32_16x16x32_bf16(af[m], bfv[n], acc[m][n], 0, 0, 0);
    __builtin_amdgcn_s_setprio(0);
    __builtin_amdgcn_s_barrier();
  }
#undef GSTAGE

  const int er = (lane >> 4) * 4;
  const int ec = lane & 15;
#pragma unroll
  for (int m = 0; m < 4; ++m) {
#pragma unroll
    for (int n = 0; n < 4; ++n) {
      const int colL = bcolL + wc + n*16 + ec;
      const float bv = bias[colL];
      const int rowb = brow + wr + m*16 + er;
      if (MODE == 0) {
        const int bi = rowb >> 11, s = rowb & 2047;
        const int hh = colL >> 6, dd = colL & 63;
        if (which == 2) {
          bf16x4 v4 = {(__bf16)(acc[m][n][0] + bv), (__bf16)(acc[m][n][1] + bv),
                       (__bf16)(acc[m][n][2] + bv), (__bf16)(acc[m][n][3] + bv)};
          *(bf16x4*)((__bf16*)vout + ((size_t)(bi*NHEADS + hh)*HDIM + dd)*SEQ + s) = v4;
        } else if (which == 0) {
          __bf16* o = (__bf16*)qout;
#pragma unroll
          for (int j = 0; j < 4; ++j)
            o[((size_t)(bi*NHEADS + hh)*SEQ + s + j)*HDIM + dd] =
                (__bf16)((acc[m][n][j] + bv) * QSCALE);
        } else {
          __bf16* o = (__bf16*)kout;
#pragma unroll
          for (int j = 0; j < 4; ++j)
            o[((size_t)(bi*NHEADS + hh)*SEQ + s + j)*HDIM + dd] = (__bf16)(acc[m][n][j] + bv);
        }
      } else {
#pragma unroll
        for (int j = 0; j < 4; ++j)
          outf[(size_t)(rowb + j)*DMODEL + colL] = acc[m][n][j] + bv;
      }
    }
  }
}

// Flash attention, fixed-shift softmax, MAX-OCCUPANCY key-split form:
// 8-wave blocks (512 thr), 4 row-waves x 2 key-groups; single-buffered K/V
// per group; P tiles live in K's space (K dead after QK^T). LDS = 32 KiB
// -> 4 blocks/CU (wave-capped) = 32 waves/CU; grid (32,32) = 1024 blocks
// ALL resident; serpentine qt map balances per-CU work (sum h0 = 34).
// 3 barriers/step. Q pre-scaled in GEMM -> exp2 direct. Fixed-shift merge:
// group1 adds its O-numerator + l via LDS at the end.
__global__ __launch_bounds__(512, 8)
void attn_fwd(const unsigned short* __restrict__ qb,
              const unsigned short* __restrict__ kb,
              const unsigned short* __restrict__ vtb,
              const int* __restrict__ ids,
              unsigned short* __restrict__ outb)
{
  const int hb = blockIdx.x;
  const int h = hb & 15, bi = hb >> 4;
  const int y = blockIdx.y;
  const int jm = y >> 3, mm = y & 7;
  const int qt = jm*8 + ((jm & 1) ? 7 - mm : mm);   // CU-balanced

  const int tid = threadIdx.x, wid = tid >> 6, lane = tid & 63;
  const int grp  = wid >> 2;            // key-half group
  const int wid4 = wid & 3;             // row-wave within group
  const int qbase = qt * 64;
  const size_t hoff = (size_t)(bi*NHEADS + h) * SEQ * HDIM;
  const unsigned short* Qh  = qb  + hoff;
  const unsigned short* Kh  = kb  + hoff;
  const unsigned short* Vth = vtb + hoff;   // [d][s]

  __shared__ unsigned short Ks[2][64*64];   // [grp] 16 KiB; P reuses this
  __shared__ unsigned short Vs[2][64*64];   // [grp] 16 KiB -> 32 KiB total
  float* LOf = (float*)Vs;                  // post-loop merge: 64x64 f32
  float* Ll  = (float*)Ks;                  // post-loop merge: 64 f32

  const int q_   = lane & 15;
  const int hi4  = lane >> 4;
  const int koff = hi4 * 4;
  const int qg = qbase + wid4*16 + q_;

  bf16x8 qf[2];
#pragma unroll
  for (int c = 0; c < 2; ++c)
    qf[c] = *(const bf16x8*)(Qh + (size_t)qg*HDIM + c*32 + hi4*8);

  // staging: per group (256 thr), tile = 512 16B-chunks; covers gt, gt+256
  const int gt = tid & 255;
  const int r0 = gt >> 3;                         // 0..31 (+32)
  const int sw = ((gt & 7) ^ (r0 & 7)) * 8;
  unsigned short* Pw = Ks[grp] + wid4*1024;       // wave's 16x64 P slice

#define STAGE(T) do {                                                          \
    const unsigned short* kbase_ = Kh + (size_t)((T)*64) * HDIM;               \
    const unsigned short* vbase_ = Vth + (T)*64;                               \
    __builtin_amdgcn_global_load_lds((gvoid*)(kbase_ + r0*64 + sw),            \
                                     (lvoid*)(Ks[grp] + gt*8), 16, 0, 0);      \
    __builtin_amdgcn_global_load_lds((gvoid*)(kbase_ + (r0+32)*64 + sw),       \
                                     (lvoid*)(Ks[grp] + (gt+256)*8), 16, 0, 0);\
    __builtin_amdgcn_global_load_lds((gvoid*)(vbase_ + (size_t)r0*SEQ + sw),   \
                                     (lvoid*)(Vs[grp] + gt*8), 16, 0, 0);      \
    __builtin_amdgcn_global_load_lds((gvoid*)(vbase_ + (size_t)(r0+32)*SEQ + sw),\
                                     (lvoid*)(Vs[grp] + (gt+256)*8), 16, 0, 0);\
  } while (0)

  float lsum = 0.f;
  floatx4 Oacc[4] = {};

  const int nT = qt + 1;
  const int h0 = (nT + 1) >> 1;               // iterations (group0 count)
  const int cnt = (grp == 0) ? h0 : nT - h0;
  const int tb  = (grp == 0) ? 0 : h0;

  for (int i = 0; i < h0; ++i) {
    const bool valid = (i < cnt);
    const int t = tb + i;
    const int kb0 = t * 64;
    int pvv = 1;
    if (valid) {
      pvv = ids[bi*SEQ + kb0 + lane];
      STAGE(t);
    }
    asm volatile("s_waitcnt vmcnt(0)" ::: "memory");
    const unsigned long long wm = __ballot(pvv == 0);
    __builtin_amdgcn_s_barrier();               // K/V ready
    __builtin_amdgcn_sched_barrier(0);

    floatx4 st[4];
    if (valid) {
#pragma unroll
      for (int t2 = 0; t2 < 4; ++t2) {
        st[t2] = (floatx4){0.f, 0.f, 0.f, 0.f};
        const int kr = t2*16 + q_;
#pragma unroll
        for (int c = 0; c < 2; ++c) {
          const int cd = ((c*4 + hi4) ^ (kr & 7)) * 8;
          bf16x8 kf = *(const bf16x8*)(Ks[grp] + kr*64 + cd);
          st[t2] = __builtin_amdgcn_mfma_f32_16x16x32_bf16(kf, qf[c], st[t2], 0, 0, 0);
        }
      }
    }
    __syncthreads();                            // K reads done -> P may overwrite

    if (valid) {
      const bool maskstep = (t == nT - 1) || (wm != 0ull);
      float p[16];
      if (!maskstep) {
#pragma unroll
        for (int j = 0; j < 16; ++j) p[j] = exp2f(st[j >> 2][j & 3]);
      } else {
#pragma unroll
        for (int t2 = 0; t2 < 4; ++t2)
#pragma unroll
          for (int r = 0; r < 4; ++r) {
            const int ko = t2*16 + koff + r;
            const bool dead = ((kb0 + ko) > qg) || (((wm >> ko) & 1ull) != 0ull);
            p[t2*4+r] = dead ? 0.f : exp2f(st[t2][r]);
          }
      }
      float ps = 0.f;
#pragma unroll
      for (int t2 = 0; t2 < 4; ++t2) {
        ps += ((p[t2*4] + p[t2*4+1]) + (p[t2*4+2] + p[t2*4+3]));
        bf16x4 pk = {(__bf16)p[t2*4], (__bf16)p[t2*4+1], (__bf16)p[t2*4+2], (__bf16)p[t2*4+3]};
        const int ko = t2*16 + koff;
        *(bf16x4*)(Pw + q_*64 + (((ko >> 3) ^ (q_ & 7)) * 8) + (ko & 7)) = pk;
      }
      lsum += ps;

      __builtin_amdgcn_s_setprio(1);
#pragma unroll
      for (int cp = 0; cp < 2; ++cp) {
        const int ko = cp*32 + hi4*8;
        bf16x8 pf = *(const bf16x8*)(Pw + q_*64 + (((ko >> 3) ^ (q_ & 7)) * 8));
#pragma unroll
        for (int n = 0; n < 4; ++n) {
          const int d = n*16 + q_;
          const int cd = ((cp*4 + hi4) ^ (d & 7)) * 8;
          bf16x8 vf = *(const bf16x8*)(Vs[grp] + d*64 + cd);
          Oacc[n] = __builtin_amdgcn_mfma_f32_16x16x32_bf16(pf, vf, Oacc[n], 0, 0, 0);
        }
      }
      __builtin_amdgcn_s_setprio(0);
    }
    __syncthreads();                            // P/V reads done -> restage safe
  }
#undef STAGE

  // per-group l reduce
  float lt = lsum + __shfl_xor(lsum, 16);
  lt += __shfl_xor(lt, 32);

  // merge: group1 -> LDS (f32 numerators + l), group0 adds + normalizes
  if (grp == 1) {
#pragma unroll
    for (int r = 0; r < 4; ++r)
#pragma unroll
      for (int n = 0; n < 4; ++n)
        LOf[(wid4*16 + koff + r)*64 + n*16 + q_] = Oacc[n][r];
    if (hi4 == 0) Ll[wid4*16 + q_] = lt;
  }
  __syncthreads();
  if (grp == 0) {
#pragma unroll
    for (int r = 0; r < 4; ++r) {
      const int rloc = wid4*16 + koff + r;
      const float inv = 1.f / (__shfl(lt, koff + r) + Ll[rloc]);
      const int row = bi*SEQ + qbase + rloc;
#pragma unroll
      for (int n = 0; n < 4; ++n) {
        const float o = Oacc[n][r] + LOf[rloc*64 + n*16 + q_];
        ((__bf16*)outb)[(size_t)row*DMODEL + h*HDIM + n*16 + q_] = (__bf16)(o * inv);
      }
    }
  }
}

extern "C" void kernel_launch(void* const* d_in, const int* in_sizes, int n_in,
                              void* d_out, int out_size, void* d_ws, size_t ws_size,
                              hipStream_t stream)
{
  const float* x  = (const float*)d_in[0];
  const int*   ids= (const int*)d_in[1];
  const float* Wq = (const float*)d_in[2];
  const float* bq = (const float*)d_in[3];
  const float* Wk = (const float*)d_in[4];
  const float* bk = (const float*)d_in[5];
  const float* Wv = (const float*)d_in[6];
  const float* bv = (const float*)d_in[7];
  const float* Wo = (const float*)d_in[8];
  const float* bo = (const float*)d_in[9];
  float* out = (float*)d_out;

  char* ws = (char*)d_ws;
  unsigned short* xb   = (unsigned short*)(ws);
  unsigned short* wqb  = (unsigned short*)(ws + ( 8u<<20));
  unsigned short* wkb  = (unsigned short*)(ws + (10u<<20));
  unsigned short* wvb  = (unsigned short*)(ws + (12u<<20));
  unsigned short* wob  = (unsigned short*)(ws + (14u<<20));
  unsigned short* qbuf = (unsigned short*)(ws + (16u<<20));
  unsigned short* kbuf = (unsigned short*)(ws + (24u<<20));
  unsigned short* vbuf = (unsigned short*)(ws + (32u<<20));  // [b,h,d,s]
  unsigned short* abuf = (unsigned short*)(ws + (40u<<20));

  cast_all<<<8192, 256, 0, stream>>>(x, Wq, Wk, Wv, Wo,
                                     (__bf16*)xb, (__bf16*)wqb, (__bf16*)wkb,
                                     (__bf16*)wvb, (__bf16*)wob);

  gemm_nt<0><<<768, 256, 0, stream>>>(xb, wqb, wkb, wvb, bq, bk, bv,
                                      qbuf, kbuf, vbuf, nullptr);

  attn_fwd<<<dim3(32, 32), 512, 0, stream>>>(qbuf, kbuf, vbuf, ids, abuf);

  gemm_nt<1><<<256, 256, 0, stream>>>(abuf, wob, wob, wob, bo, bo, bo,
                                      nullptr, nullptr, nullptr, out);
}

// Round 13
// 119.217 us; speedup vs baseline: 1.9851x; 1.9851x over previous
//
#include <hip/hip_runtime.h>

#define DMODEL 1024
#define NHEADS 16
#define HDIM   64
#define BATCH  2
#define SEQ    2048
#define MROWS  (BATCH*SEQ)

typedef __bf16 bf16x8 __attribute__((ext_vector_type(8)));
typedef __bf16 bf16x4 __attribute__((ext_vector_type(4)));
typedef float floatx4 __attribute__((ext_vector_type(4)));

typedef const __attribute__((address_space(1))) void gvoid;
typedef __attribute__((address_space(3))) void lvoid;

// Q pre-scale: 1/sqrt(64) * log2(e), folded into the QKV GEMM epilogue.
#define QSCALE 0.18033688011112042f

// Single cast kernel: x (1048576 float4) then Wq/Wk/Wv/Wo (262144 float4 each).
__global__ void cast_all(const float* __restrict__ x,
                         const float* __restrict__ wq, const float* __restrict__ wk,
                         const float* __restrict__ wv, const float* __restrict__ wo,
                         __bf16* __restrict__ xb, __bf16* __restrict__ wqb,
                         __bf16* __restrict__ wkb, __bf16* __restrict__ wvb,
                         __bf16* __restrict__ wob)
{
  const int i = blockIdx.x * 256 + threadIdx.x;
  const float* s; __bf16* o; int off;
  if (i < MROWS*DMODEL/4) { s = x; o = xb; off = i; }
  else {
    const int r = i - MROWS*DMODEL/4;
    const int w = r >> 18;
    off = r & 262143;
    s = (w == 0) ? wq : (w == 1) ? wk : (w == 2) ? wv : wo;
    o = (w == 0) ? wqb : (w == 1) ? wkb : (w == 2) ? wvb : wob;
  }
  const float4 f = ((const float4*)s)[off];
  bf16x4 v = {(__bf16)f.x, (__bf16)f.y, (__bf16)f.z, (__bf16)f.w};
  *(bf16x4*)(o + off*4) = v;
}

// NT GEMM (unchanged): double-buffered gload_lds + vmcnt(4).
template<int MODE>
__global__ __launch_bounds__(256, 3)
void gemm_nt(const unsigned short* __restrict__ A,
             const unsigned short* __restrict__ W0,
             const unsigned short* __restrict__ W1,
             const unsigned short* __restrict__ W2,
             const float* __restrict__ b0,
             const float* __restrict__ b1,
             const float* __restrict__ b2,
             unsigned short* __restrict__ qout,
             unsigned short* __restrict__ kout,
             unsigned short* __restrict__ vout,
             float* __restrict__ outf)
{
  const int K = DMODEL;
  __shared__ unsigned short As[2][128*32];
  __shared__ unsigned short Bs[2][128*32];
  const int tid  = threadIdx.x;
  const int wid  = tid >> 6;
  const int lane = tid & 63;

  const int lin = blockIdx.x;
  const int wg  = (MODE == 0) ? ((lin & 7)*96 + (lin >> 3))
                              : ((lin & 7)*32 + (lin >> 3));
  const int bx  = (MODE == 0) ? (wg % 24) : (wg & 7);
  const int by  = (MODE == 0) ? (wg / 24) : (wg >> 3);
  const int brow = by * 128;
  const int bcol = bx * 128;
  const int wr = (wid >> 1) * 64;
  const int wc = (wid & 1) * 64;

  int which = 0;
  const unsigned short* Bw = W0;
  const float* bias = b0;
  int bcolL = bcol;
  if (MODE == 0) {
    which = bcol >> 10;
    Bw   = which == 0 ? W0 : which == 1 ? W1 : W2;
    bias = which == 0 ? b0 : which == 1 ? b1 : b2;
    bcolL = bcol & 1023;
  }

  floatx4 acc[4][4] = {};

  const int sr = wid*16 + (lane >> 2);
  const int sc = (lane & 3) * 8;
  const int fr = lane & 15;
  const int fk = (lane >> 4) * 8;

#define GSTAGE(KT, B) do {                                                     \
    _Pragma("unroll")                                                          \
    for (int i_ = 0; i_ < 2; ++i_) {                                           \
      __builtin_amdgcn_global_load_lds(                                        \
          (gvoid*)(A + (size_t)(brow + i_*64 + sr)*K + (KT) + sc),             \
          (lvoid*)(As[B] + i_*2048 + wid*512), 16, 0, 0);                      \
      __builtin_amdgcn_global_load_lds(                                        \
          (gvoid*)(Bw + (size_t)(bcolL + i_*64 + sr)*K + (KT) + sc),           \
          (lvoid*)(Bs[B] + i_*2048 + wid*512), 16, 0, 0);                      \
    }                                                                          \
  } while (0)

  GSTAGE(0, 0);

  for (int kt = 0; kt < K; kt += 32) {
    const int cur = (kt >> 5) & 1;
    if (kt + 32 < K) {
      GSTAGE(kt + 32, cur ^ 1);
      asm volatile("s_waitcnt vmcnt(4)" ::: "memory");
    } else {
      asm volatile("s_waitcnt vmcnt(0)" ::: "memory");
    }
    __builtin_amdgcn_s_barrier();
    __builtin_amdgcn_sched_barrier(0);

    bf16x8 af[4], bfv[4];
#pragma unroll
    for (int m = 0; m < 4; ++m)
      af[m] = *(const bf16x8*)(As[cur] + (wr + m*16 + fr)*32 + fk);
#pragma unroll
    for (int n = 0; n < 4; ++n)
      bfv[n] = *(const bf16x8*)(Bs[cur] + (wc + n*16 + fr)*32 + fk);
    __builtin_amdgcn_s_setprio(1);
#pragma unroll
    for (int m = 0; m < 4; ++m)
#pragma unroll
      for (int n = 0; n < 4; ++n)
        acc[m][n] = __builtin_amdgcn_mfma_f32_16x16x32_bf16(af[m], bfv[n], acc[m][n], 0, 0, 0);
    __builtin_amdgcn_s_setprio(0);
    __builtin_amdgcn_s_barrier();
  }
#undef GSTAGE

  const int er = (lane >> 4) * 4;
  const int ec = lane & 15;
#pragma unroll
  for (int m = 0; m < 4; ++m) {
#pragma unroll
    for (int n = 0; n < 4; ++n) {
      const int colL = bcolL + wc + n*16 + ec;
      const float bv = bias[colL];
      const int rowb = brow + wr + m*16 + er;
      if (MODE == 0) {
        const int bi = rowb >> 11, s = rowb & 2047;
        const int hh = colL >> 6, dd = colL & 63;
        if (which == 2) {
          bf16x4 v4 = {(__bf16)(acc[m][n][0] + bv), (__bf16)(acc[m][n][1] + bv),
                       (__bf16)(acc[m][n][2] + bv), (__bf16)(acc[m][n][3] + bv)};
          *(bf16x4*)((__bf16*)vout + ((size_t)(bi*NHEADS + hh)*HDIM + dd)*SEQ + s) = v4;
        } else if (which == 0) {
          __bf16* o = (__bf16*)qout;
#pragma unroll
          for (int j = 0; j < 4; ++j)
            o[((size_t)(bi*NHEADS + hh)*SEQ + s + j)*HDIM + dd] =
                (__bf16)((acc[m][n][j] + bv) * QSCALE);
        } else {
          __bf16* o = (__bf16*)kout;
#pragma unroll
          for (int j = 0; j < 4; ++j)
            o[((size_t)(bi*NHEADS + hh)*SEQ + s + j)*HDIM + dd] = (__bf16)(acc[m][n][j] + bv);
        }
      } else {
#pragma unroll
        for (int j = 0; j < 4; ++j)
          outf[(size_t)(rowb + j)*DMODEL + colL] = acc[m][n][j] + bv;
      }
    }
  }
}

// Flash attention, fixed-shift softmax, key-split, 32 KiB LDS.
// 8-wave blocks (512 thr), 4 row-waves x 2 key-groups; single-buffered K/V;
// P tiles reuse K's space. __launch_bounds__(512,4): VGPR cap 128 — r11's
// near-identical code compiled at 64 VGPR, which naturally allows 8 waves/EU;
// LDS 32 KiB allows 5 blocks/CU; wave cap -> 4 blocks/CU = 32 waves/CU.
// (512,8) FORCED 64-reg cap and spilled catastrophically — never do that.
__global__ __launch_bounds__(512, 4)
void attn_fwd(const unsigned short* __restrict__ qb,
              const unsigned short* __restrict__ kb,
              const unsigned short* __restrict__ vtb,
              const int* __restrict__ ids,
              unsigned short* __restrict__ outb)
{
  const int hb = blockIdx.x;
  const int h = hb & 15, bi = hb >> 4;
  const int y = blockIdx.y;
  const int jm = y >> 3, mm = y & 7;
  const int qt = jm*8 + ((jm & 1) ? 7 - mm : mm);   // CU-balanced

  const int tid = threadIdx.x, wid = tid >> 6, lane = tid & 63;
  const int grp  = wid >> 2;            // key-half group
  const int wid4 = wid & 3;             // row-wave within group
  const int qbase = qt * 64;
  const size_t hoff = (size_t)(bi*NHEADS + h) * SEQ * HDIM;
  const unsigned short* Qh  = qb  + hoff;
  const unsigned short* Kh  = kb  + hoff;
  const unsigned short* Vth = vtb + hoff;   // [d][s]

  __shared__ unsigned short Ks[2][64*64];   // [grp] 16 KiB; P reuses this
  __shared__ unsigned short Vs[2][64*64];   // [grp] 16 KiB -> 32 KiB total
  float* LOf = (float*)Vs;                  // post-loop merge: 64x64 f32
  float* Ll  = (float*)Ks;                  // post-loop merge: 64 f32

  const int q_   = lane & 15;
  const int hi4  = lane >> 4;
  const int koff = hi4 * 4;
  const int qg = qbase + wid4*16 + q_;

  bf16x8 qf[2];
#pragma unroll
  for (int c = 0; c < 2; ++c)
    qf[c] = *(const bf16x8*)(Qh + (size_t)qg*HDIM + c*32 + hi4*8);

  // staging: per group (256 thr), tile = 512 16B-chunks; covers gt, gt+256
  const int gt = tid & 255;
  const int r0 = gt >> 3;                         // 0..31 (+32)
  const int sw = ((gt & 7) ^ (r0 & 7)) * 8;
  unsigned short* Pw = Ks[grp] + wid4*1024;       // wave's 16x64 P slice

#define STAGE(T) do {                                                          \
    const unsigned short* kbase_ = Kh + (size_t)((T)*64) * HDIM;               \
    const unsigned short* vbase_ = Vth + (T)*64;                               \
    __builtin_amdgcn_global_load_lds((gvoid*)(kbase_ + r0*64 + sw),            \
                                     (lvoid*)(Ks[grp] + gt*8), 16, 0, 0);      \
    __builtin_amdgcn_global_load_lds((gvoid*)(kbase_ + (r0+32)*64 + sw),       \
                                     (lvoid*)(Ks[grp] + (gt+256)*8), 16, 0, 0);\
    __builtin_amdgcn_global_load_lds((gvoid*)(vbase_ + (size_t)r0*SEQ + sw),   \
                                     (lvoid*)(Vs[grp] + gt*8), 16, 0, 0);      \
    __builtin_amdgcn_global_load_lds((gvoid*)(vbase_ + (size_t)(r0+32)*SEQ + sw),\
                                     (lvoid*)(Vs[grp] + (gt+256)*8), 16, 0, 0);\
  } while (0)

  float lsum = 0.f;
  floatx4 Oacc[4] = {};

  const int nT = qt + 1;
  const int h0 = (nT + 1) >> 1;               // iterations (group0 count)
  const int cnt = (grp == 0) ? h0 : nT - h0;
  const int tb  = (grp == 0) ? 0 : h0;

  for (int i = 0; i < h0; ++i) {
    const bool valid = (i < cnt);
    const int t = tb + i;
    const int kb0 = t * 64;
    int pvv = 1;
    if (valid) {
      pvv = ids[bi*SEQ + kb0 + lane];
      STAGE(t);
    }
    asm volatile("s_waitcnt vmcnt(0)" ::: "memory");
    const unsigned long long wm = __ballot(pvv == 0);
    __builtin_amdgcn_s_barrier();               // K/V ready
    __builtin_amdgcn_sched_barrier(0);

    floatx4 st[4];
    if (valid) {
#pragma unroll
      for (int t2 = 0; t2 < 4; ++t2) {
        st[t2] = (floatx4){0.f, 0.f, 0.f, 0.f};
        const int kr = t2*16 + q_;
#pragma unroll
        for (int c = 0; c < 2; ++c) {
          const int cd = ((c*4 + hi4) ^ (kr & 7)) * 8;
          bf16x8 kf = *(const bf16x8*)(Ks[grp] + kr*64 + cd);
          st[t2] = __builtin_amdgcn_mfma_f32_16x16x32_bf16(kf, qf[c], st[t2], 0, 0, 0);
        }
      }
    }
    __syncthreads();                            // K reads done -> P may overwrite

    if (valid) {
      const bool maskstep = (t == nT - 1) || (wm != 0ull);
      float p[16];
      if (!maskstep) {
#pragma unroll
        for (int j = 0; j < 16; ++j) p[j] = exp2f(st[j >> 2][j & 3]);
      } else {
#pragma unroll
        for (int t2 = 0; t2 < 4; ++t2)
#pragma unroll
          for (int r = 0; r < 4; ++r) {
            const int ko = t2*16 + koff + r;
            const bool dead = ((kb0 + ko) > qg) || (((wm >> ko) & 1ull) != 0ull);
            p[t2*4+r] = dead ? 0.f : exp2f(st[t2][r]);
          }
      }
      float ps = 0.f;
#pragma unroll
      for (int t2 = 0; t2 < 4; ++t2) {
        ps += ((p[t2*4] + p[t2*4+1]) + (p[t2*4+2] + p[t2*4+3]));
        bf16x4 pk = {(__bf16)p[t2*4], (__bf16)p[t2*4+1], (__bf16)p[t2*4+2], (__bf16)p[t2*4+3]};
        const int ko = t2*16 + koff;
        *(bf16x4*)(Pw + q_*64 + (((ko >> 3) ^ (q_ & 7)) * 8) + (ko & 7)) = pk;
      }
      lsum += ps;

      __builtin_amdgcn_s_setprio(1);
#pragma unroll
      for (int cp = 0; cp < 2; ++cp) {
        const int ko = cp*32 + hi4*8;
        bf16x8 pf = *(const bf16x8*)(Pw + q_*64 + (((ko >> 3) ^ (q_ & 7)) * 8));
#pragma unroll
        for (int n = 0; n < 4; ++n) {
          const int d = n*16 + q_;
          const int cd = ((cp*4 + hi4) ^ (d & 7)) * 8;
          bf16x8 vf = *(const bf16x8*)(Vs[grp] + d*64 + cd);
          Oacc[n] = __builtin_amdgcn_mfma_f32_16x16x32_bf16(pf, vf, Oacc[n], 0, 0, 0);
        }
      }
      __builtin_amdgcn_s_setprio(0);
    }
    __syncthreads();                            // P/V reads done -> restage safe
  }
#undef STAGE

  // per-group l reduce
  float lt = lsum + __shfl_xor(lsum, 16);
  lt += __shfl_xor(lt, 32);

  // merge: group1 -> LDS (f32 numerators + l), group0 adds + normalizes
  if (grp == 1) {
#pragma unroll
    for (int r = 0; r < 4; ++r)
#pragma unroll
      for (int n = 0; n < 4; ++n)
        LOf[(wid4*16 + koff + r)*64 + n*16 + q_] = Oacc[n][r];
    if (hi4 == 0) Ll[wid4*16 + q_] = lt;
  }
  __syncthreads();
  if (grp == 0) {
#pragma unroll
    for (int r = 0; r < 4; ++r) {
      const int rloc = wid4*16 + koff + r;
      const float inv = 1.f / (__shfl(lt, koff + r) + Ll[rloc]);
      const int row = bi*SEQ + qbase + rloc;
#pragma unroll
      for (int n = 0; n < 4; ++n) {
        const float o = Oacc[n][r] + LOf[rloc*64 + n*16 + q_];
        ((__bf16*)outb)[(size_t)row*DMODEL + h*HDIM + n*16 + q_] = (__bf16)(o * inv);
      }
    }
  }
}

extern "C" void kernel_launch(void* const* d_in, const int* in_sizes, int n_in,
                              void* d_out, int out_size, void* d_ws, size_t ws_size,
                              hipStream_t stream)
{
  const float* x  = (const float*)d_in[0];
  const int*   ids= (const int*)d_in[1];
  const float* Wq = (const float*)d_in[2];
  const float* bq = (const float*)d_in[3];
  const float* Wk = (const float*)d_in[4];
  const float* bk = (const float*)d_in[5];
  const float* Wv = (const float*)d_in[6];
  const float* bv = (const float*)d_in[7];
  const float* Wo = (const float*)d_in[8];
  const float* bo = (const float*)d_in[9];
  float* out = (float*)d_out;

  char* ws = (char*)d_ws;
  unsigned short* xb   = (unsigned short*)(ws);
  unsigned short* wqb  = (unsigned short*)(ws + ( 8u<<20));
  unsigned short* wkb  = (unsigned short*)(ws + (10u<<20));
  unsigned short* wvb  = (unsigned short*)(ws + (12u<<20));
  unsigned short* wob  = (unsigned short*)(ws + (14u<<20));
  unsigned short* qbuf = (unsigned short*)(ws + (16u<<20));
  unsigned short* kbuf = (unsigned short*)(ws + (24u<<20));
  unsigned short* vbuf = (unsigned short*)(ws + (32u<<20));  // [b,h,d,s]
  unsigned short* abuf = (unsigned short*)(ws + (40u<<20));

  cast_all<<<8192, 256, 0, stream>>>(x, Wq, Wk, Wv, Wo,
                                     (__bf16*)xb, (__bf16*)wqb, (__bf16*)wkb,
                                     (__bf16*)wvb, (__bf16*)wob);

  gemm_nt<0><<<768, 256, 0, stream>>>(xb, wqb, wkb, wvb, bq, bk, bv,
                                      qbuf, kbuf, vbuf, nullptr);

  attn_fwd<<<dim3(32, 32), 512, 0, stream>>>(qbuf, kbuf, vbuf, ids, abuf);

  gemm_nt<1><<<256, 256, 0, stream>>>(abuf, wob, wob, wob, bo, bo, bo,
                                      nullptr, nullptr, nullptr, out);
}